// Round 9
// baseline (7389.899 us; speedup 1.0000x reference)
//
#include <hip/hip_runtime.h>
#include <stdint.h>

// ---------------- types / helpers ----------------
typedef short bf16x8 __attribute__((ext_vector_type(8)));
typedef float f32x4  __attribute__((ext_vector_type(4)));

__device__ static inline unsigned short f2bf(float v){
  unsigned x = __float_as_uint(v);
  unsigned r = (x + 0x7fffu + ((x >> 16) & 1u)) >> 16;
  return (unsigned short)r;
}

#define GLOAD16(g, l) \
  __builtin_amdgcn_global_load_lds((const __attribute__((address_space(1))) void*)(g), \
                                   (__attribute__((address_space(3))) void*)(l), 16, 0, 0)

__device__ static inline f32x4 mfma16(bf16x8 a, bf16x8 b, f32x4 c){
  return __builtin_amdgcn_mfma_f32_16x16x32_bf16(a, b, c, 0, 0, 0);
}

// ---------------- prep: weight bf16 round + gate-interleave reorder ----------------
// dst row r = 4*u + g  <-  src row g*1024 + u   (g: 0=i,1=f,2=g,3=o)
__global__ void k_prep_w(const float* __restrict__ Whh0,
                         const float* __restrict__ Wih1, const float* __restrict__ Whh1,
                         unsigned short* __restrict__ W0hi, unsigned short* __restrict__ W1hi)
{
  const long n0 = (long)4096 * 1024;
  const long n1 = (long)4096 * 2048;
  long stride = (long)gridDim.x * blockDim.x;
  for (long idx = (long)blockIdx.x * blockDim.x + threadIdx.x; idx < n0 + n1; idx += stride){
    if (idx < n0){
      int i = (int)idx;
      int r = i >> 10, k = i & 1023;
      int u = r >> 2, g = r & 3;
      W0hi[i] = f2bf(Whh0[(size_t)(g * 1024 + u) * 1024 + k]);
    } else {
      long i = idx - n0;
      int r = (int)(i >> 11), k = (int)(i & 2047);
      int u = r >> 2, g = r & 3;
      int srow = g * 1024 + u;
      float v = (k < 1024) ? Wih1[(size_t)srow * 1024 + k]
                           : Whh1[(size_t)srow * 1024 + (k - 1024)];
      W1hi[i] = f2bf(v);
    }
  }
}

// ---------------- prep: x-proj+bias (reordered), b1r, zero states, init out ----------------
__global__ void k_prep_misc(const float* __restrict__ x, const float* __restrict__ Wih0,
                            const float* __restrict__ bih0, const float* __restrict__ bhh0,
                            const float* __restrict__ bih1, const float* __restrict__ bhh1,
                            const float* __restrict__ bfc,
                            float* __restrict__ xb0, float* __restrict__ b1r,
                            unsigned short* __restrict__ XAhi,
                            float* __restrict__ c0, float* __restrict__ c1,
                            float* __restrict__ out)
{
  const long NXB = (long)512 * 4096;          // xb0
  const long NXA = (long)2 * 512 * 2048;      // XA (2 parities)
  const long NC  = (long)512 * 1024;
  const long NO  = (long)512 * 106 * 2;
  const long total = NXB + 4096 + NXA + 2 * NC + NO;
  long stride = (long)gridDim.x * blockDim.x;
  for (long idx = (long)blockIdx.x * blockDim.x + threadIdx.x; idx < total; idx += stride){
    long t = idx;
    if (t < NXB){
      int m = (int)(t >> 12), c = (int)(t & 4095);
      int u = c >> 2, g = c & 3;
      int row = g * 1024 + u;
      xb0[t] = x[m * 2 + 0] * Wih0[row * 2 + 0] + x[m * 2 + 1] * Wih0[row * 2 + 1]
             + bih0[row] + bhh0[row];
      continue;
    }
    t -= NXB;
    if (t < 4096){
      int c = (int)t; int u = c >> 2, g = c & 3; int row = g * 1024 + u;
      b1r[c] = bih1[row] + bhh1[row]; continue;
    }
    t -= 4096;
    if (t < NXA){ XAhi[t] = 0; continue; } t -= NXA;
    if (t < NC){ c0[t] = 0.f; continue; } t -= NC;
    if (t < NC){ c1[t] = 0.f; continue; } t -= NC;
    out[t] = bfc[t & 1];
  }
}

// ---------------- fused step kernel: bf16 GEMM + LSTM pointwise (+FC) ----------------
// gates[m, 4u+g] = sum_k A[m,k]*W[4u+g,k] ; single bf16 product.
// Tile BM=128, BN=128, BK=64; 4 waves (2x2), wave tile 64x64; grid 128.
// Rationale: staging traffic = nblocks*(BM+BN)*K is the measured aggregate ceiling
// (~9 TB/s); 128x128 tiles cut it 295->201 MB/pair and halve LDS reads (32 FLOP/B).
// 4-stage LDS ring (32KB/stage: A 16K|B 16K), 3-ahead prefetch, counted vmcnt.
// A rows live in XA [512][2048] bf16, row stride 2048 elements.
__global__ __launch_bounds__(256, 1) void k_lstm_step(
  const unsigned short* __restrict__ Ahi,
  const unsigned short* __restrict__ Whi,
  const float* __restrict__ addv, int addIsMat,
  float* __restrict__ cbuf,
  unsigned short* __restrict__ Hhi_out,
  const float* __restrict__ Wfc, float* __restrict__ pred, int tstep,
  int Kw, int NS)
{
  __shared__ char lds[131072];   // 4 stage buffers x 32KB
  const int tid = threadIdx.x;
  const int wid = tid >> 6, lane = tid & 63;

  // XCD-grouped mapping: 16 blocks per XCD = 4 N-tiles x 4 M-tiles (grid 128, bijective)
  int L = blockIdx.x;
  int xc = L & 7, j = L >> 3;
  int ntile = xc * 4 + (j & 3);          // 0..31
  int mtile = j >> 2;                    // 0..3
  int m0 = mtile * 128, n0 = ntile * 128;
  int wm = wid >> 1, wn = wid & 1;

  // ---- staging state (hoisted): wave owns 8 x 1KB segments of the 32KB stage ----
  // segs 0..15 = A rows (128 x 128B), segs 16..31 = B rows (128 x 128B)
  int rsub  = lane >> 3;                    // row within 8-row octet
  int col16 = (lane & 7) ^ rsub;            // pre-swizzled 16B-chunk column (involution)
  const unsigned short* gp[8];              // per-segment global pointers, advance 64/stage
  int segByte[8];                           // wave-uniform LDS byte offset within stage
  #pragma unroll
  for (int i = 0; i < 8; i++){
    int sg = wid * 8 + i;
    if (sg < 16){
      int row = sg * 8 + rsub;              // 0..127
      gp[i] = Ahi + (size_t)(m0 + row) * 2048 + col16 * 8;
      segByte[i] = sg * 1024;
    } else {
      int row = (sg - 16) * 8 + rsub;       // 0..127
      gp[i] = Whi + (size_t)(n0 + row) * Kw + col16 * 8;
      segByte[i] = 16384 + (sg - 16) * 1024;
    }
  }

  // ---- compute-side swizzled fragment offsets (stage-invariant) ----
  int offA[4][2], offB[4][2];
  #pragma unroll
  for (int f = 0; f < 4; f++)
    #pragma unroll
    for (int ks = 0; ks < 2; ks++){
      int rowA = wm * 64 + f * 16 + (lane & 15);
      int rowB = wn * 64 + f * 16 + (lane & 15);
      int kb   = ks * 64 + ((lane >> 4) << 4);
      offA[f][ks] = (rowA * 128 + kb) ^ ((rowA & 7) << 4);
      offB[f][ks] = 16384 + ((rowB * 128 + kb) ^ ((rowB & 7) << 4));
    }

  f32x4 acc[4][4];
  #pragma unroll
  for (int a = 0; a < 4; a++)
    #pragma unroll
    for (int b = 0; b < 4; b++)
      acc[a][b] = (f32x4){0.f, 0.f, 0.f, 0.f};

  auto STAGE = [&](int sbuf){
    char* ldsb = lds + sbuf * 32768;
    #pragma unroll
    for (int i = 0; i < 8; i++){
      GLOAD16(gp[i], ldsb + segByte[i]);
      gp[i] += 64;
    }
  };

  STAGE(0); STAGE(1); STAGE(2);
  int cur = 0;
  for (int s = 0; s < NS; s++){
    if (s + 3 < NS){
      STAGE((cur + 3) & 3);
      asm volatile("s_waitcnt vmcnt(24)" ::: "memory");  // stage s landed; s+1..s+3 in flight
    } else if (s + 2 < NS){
      asm volatile("s_waitcnt vmcnt(16)" ::: "memory");
    } else if (s + 1 < NS){
      asm volatile("s_waitcnt vmcnt(8)" ::: "memory");
    } else {
      asm volatile("s_waitcnt vmcnt(0)" ::: "memory");
    }
    __builtin_amdgcn_s_barrier();
    asm volatile("" ::: "memory");

    const char* bb = lds + cur * 32768;
    #pragma unroll
    for (int ks = 0; ks < 2; ks++){
      bf16x8 af[4], bf[4];
      #pragma unroll
      for (int f = 0; f < 4; f++){
        af[f] = *(const bf16x8*)(bb + offA[f][ks]);
        bf[f] = *(const bf16x8*)(bb + offB[f][ks]);
      }
      #pragma unroll
      for (int fm = 0; fm < 4; fm++)
        #pragma unroll
        for (int fn = 0; fn < 4; fn++)
          acc[fm][fn] = mfma16(af[fm], bf[fn], acc[fm][fn]);
    }
    asm volatile("" ::: "memory");
    __builtin_amdgcn_s_barrier();
    cur = (cur + 1) & 3;
  }

  // ---------- epilogue: acc -> LDS gates [128][129], then pointwise LSTM ----------
  float* gl = (float*)lds;
  #pragma unroll
  for (int fm = 0; fm < 4; fm++)
    #pragma unroll
    for (int fn = 0; fn < 4; fn++)
      #pragma unroll
      for (int r = 0; r < 4; r++){
        int row = wm * 64 + fm * 16 + ((lane >> 4) << 2) + r;   // batch row in tile
        int col = wn * 64 + fn * 16 + (lane & 15);              // gate col in tile
        gl[row * 129 + col] = acc[fm][fn][r];
      }
  __syncthreads();

  #pragma unroll
  for (int it = 0; it < 16; it++){
    int u    = tid & 31;                 // unit 0..31 within tile
    int rowl = (it << 3) + (tid >> 5);   // batch row 0..127 within tile
    int gm = m0 + rowl;
    int gu = (n0 >> 2) + u;              // global unit 0..1023
    const float* grow = gl + rowl * 129 + (u << 2);
    float gi = grow[0], gf = grow[1], gg = grow[2], go = grow[3];
    if (addIsMat){
      const float* a = addv + ((size_t)gm << 12) + n0 + (u << 2);
      gi += a[0]; gf += a[1]; gg += a[2]; go += a[3];
    } else {
      const float* a = addv + n0 + (u << 2);
      gi += a[0]; gf += a[1]; gg += a[2]; go += a[3];
    }
    float ii = 1.f / (1.f + expf(-gi));
    float ff = 1.f / (1.f + expf(-gf));
    float g2 = tanhf(gg);
    float oo = 1.f / (1.f + expf(-go));
    size_t ci = ((size_t)gm << 10) + gu;
    float c = ff * cbuf[ci] + ii * g2;
    cbuf[ci] = c;
    float h = oo * tanhf(c);
    size_t hi_idx = ((size_t)gm << 11) + gu;   // XA row stride 2048 (base pre-offset per layer)
    Hhi_out[hi_idx] = f2bf(h);
    if (pred){
      float p0 = h * Wfc[gu];
      float p1 = h * Wfc[1024 + gu];
      #pragma unroll
      for (int mm = 16; mm >= 1; mm >>= 1){
        p0 += __shfl_xor(p0, mm);
        p1 += __shfl_xor(p1, mm);
      }
      if ((lane & 31) == 0){
        float* op = pred + ((size_t)gm * 106 + tstep) * 2;
        atomicAdd(op,     p0);
        atomicAdd(op + 1, p1);
      }
    }
  }
}

// ---------------- launch ----------------
extern "C" void kernel_launch(void* const* d_in, const int* in_sizes, int n_in,
                              void* d_out, int out_size, void* d_ws, size_t ws_size,
                              hipStream_t stream)
{
  (void)in_sizes; (void)n_in; (void)out_size; (void)ws_size;
  const float* x    = (const float*)d_in[0];
  const float* Wih0 = (const float*)d_in[1];
  const float* Whh0 = (const float*)d_in[2];
  const float* bih0 = (const float*)d_in[3];
  const float* bhh0 = (const float*)d_in[4];
  const float* Wih1 = (const float*)d_in[5];
  const float* Whh1 = (const float*)d_in[6];
  const float* bih1 = (const float*)d_in[7];
  const float* bhh1 = (const float*)d_in[8];
  const float* Wfc  = (const float*)d_in[9];
  const float* bfc  = (const float*)d_in[10];
  float* out = (float*)d_out;

  char* ws = (char*)d_ws;
  size_t off = 0;
  auto carve = [&](size_t bytes)->char*{
    char* p = ws + off;
    off += (bytes + 255) & ~(size_t)255;
    return p;
  };
  unsigned short* W0hi = (unsigned short*)carve((size_t)4096 * 1024 * 2);
  unsigned short* W1hi = (unsigned short*)carve((size_t)4096 * 2048 * 2);
  float*          xb0  = (float*)carve((size_t)512 * 4096 * 4);
  float*          b1r  = (float*)carve((size_t)4096 * 4);
  unsigned short* XAhi = (unsigned short*)carve((size_t)2 * 512 * 2048 * 2);
  float*          c0   = (float*)carve((size_t)512 * 1024 * 4);
  float*          c1   = (float*)carve((size_t)512 * 1024 * 4);

  k_prep_w<<<dim3(2048), dim3(256), 0, stream>>>(Whh0, Wih1, Whh1, W0hi, W1hi);
  k_prep_misc<<<dim3(2048), dim3(256), 0, stream>>>(x, Wih0, bih0, bhh0, bih1, bhh1, bfc,
                                                    xb0, b1r, XAhi, c0, c1, out);

  const int PS = 512 * 2048;   // parity stride (elements) of XA
  for (int t = 0; t < 106; t++){
    int p = t & 1;
    // layer 0: gates = h0(t-1) @ W0^T + xb0 ; A = XA[p^1] cols 0..1023 ; K=1024, NS=16
    k_lstm_step<<<dim3(128), dim3(256), 0, stream>>>(
      XAhi + (p ^ 1) * PS,
      W0hi, xb0, 1, c0,
      XAhi + p * PS,                                // h0(t) -> XA[p] cols 0..1023
      (const float*)nullptr, (float*)nullptr, t, 1024, 16);
    // layer 1: gates = [h0(t)|h1(t-1)] @ W1^T + b1 ; A = XA[p] ; K=2048, NS=32 ; + FC
    k_lstm_step<<<dim3(128), dim3(256), 0, stream>>>(
      XAhi + p * PS,
      W1hi, b1r, 0, c1,
      XAhi + (p ^ 1) * PS + 1024,                   // h1(t) -> XA[p^1] cols 1024..
      Wfc, out, t, 2048, 32);
  }
}

// Round 10
// 6679.050 us; speedup vs baseline: 1.1064x; 1.1064x over previous
//
#include <hip/hip_runtime.h>
#include <stdint.h>

// ---------------- types / helpers ----------------
typedef short bf16x8 __attribute__((ext_vector_type(8)));
typedef float f32x4  __attribute__((ext_vector_type(4)));

__device__ static inline unsigned short f2bf(float v){
  unsigned x = __float_as_uint(v);
  unsigned r = (x + 0x7fffu + ((x >> 16) & 1u)) >> 16;
  return (unsigned short)r;
}

#define GLOAD16(g, l) \
  __builtin_amdgcn_global_load_lds((const __attribute__((address_space(1))) void*)(g), \
                                   (__attribute__((address_space(3))) void*)(l), 16, 0, 0)

__device__ static inline f32x4 mfma16(bf16x8 a, bf16x8 b, f32x4 c){
  return __builtin_amdgcn_mfma_f32_16x16x32_bf16(a, b, c, 0, 0, 0);
}

// ---------------- prep: weight bf16 round + gate-interleave reorder ----------------
__global__ void k_prep_w(const float* __restrict__ Whh0,
                         const float* __restrict__ Wih1, const float* __restrict__ Whh1,
                         unsigned short* __restrict__ W0hi, unsigned short* __restrict__ W1hi)
{
  const long n0 = (long)4096 * 1024;
  const long n1 = (long)4096 * 2048;
  long stride = (long)gridDim.x * blockDim.x;
  for (long idx = (long)blockIdx.x * blockDim.x + threadIdx.x; idx < n0 + n1; idx += stride){
    if (idx < n0){
      int i = (int)idx;
      int r = i >> 10, k = i & 1023;
      int u = r >> 2, g = r & 3;
      W0hi[i] = f2bf(Whh0[(size_t)(g * 1024 + u) * 1024 + k]);
    } else {
      long i = idx - n0;
      int r = (int)(i >> 11), k = (int)(i & 2047);
      int u = r >> 2, g = r & 3;
      int srow = g * 1024 + u;
      float v = (k < 1024) ? Wih1[(size_t)srow * 1024 + k]
                           : Whh1[(size_t)srow * 1024 + (k - 1024)];
      W1hi[i] = f2bf(v);
    }
  }
}

// ---------------- prep: x-proj+bias (reordered), b1r, zero states, init out ----------------
__global__ void k_prep_misc(const float* __restrict__ x, const float* __restrict__ Wih0,
                            const float* __restrict__ bih0, const float* __restrict__ bhh0,
                            const float* __restrict__ bih1, const float* __restrict__ bhh1,
                            const float* __restrict__ bfc,
                            float* __restrict__ xb0, float* __restrict__ b1r,
                            unsigned short* __restrict__ XAhi,
                            float* __restrict__ c0, float* __restrict__ c1,
                            float* __restrict__ out)
{
  const long NXB = (long)512 * 4096;
  const long NXA = (long)2 * 512 * 2048;
  const long NC  = (long)512 * 1024;
  const long NO  = (long)512 * 106 * 2;
  const long total = NXB + 4096 + NXA + 2 * NC + NO;
  long stride = (long)gridDim.x * blockDim.x;
  for (long idx = (long)blockIdx.x * blockDim.x + threadIdx.x; idx < total; idx += stride){
    long t = idx;
    if (t < NXB){
      int m = (int)(t >> 12), c = (int)(t & 4095);
      int u = c >> 2, g = c & 3;
      int row = g * 1024 + u;
      xb0[t] = x[m * 2 + 0] * Wih0[row * 2 + 0] + x[m * 2 + 1] * Wih0[row * 2 + 1]
             + bih0[row] + bhh0[row];
      continue;
    }
    t -= NXB;
    if (t < 4096){
      int c = (int)t; int u = c >> 2, g = c & 3; int row = g * 1024 + u;
      b1r[c] = bih1[row] + bhh1[row]; continue;
    }
    t -= 4096;
    if (t < NXA){ XAhi[t] = 0; continue; } t -= NXA;
    if (t < NC){ c0[t] = 0.f; continue; } t -= NC;
    if (t < NC){ c1[t] = 0.f; continue; } t -= NC;
    out[t] = bfc[t & 1];
  }
}

// ---------------- fused step kernel: bf16 GEMM + LSTM pointwise (+FC) ----------------
// Tile BM=64, BN=128, BK=64; 8 waves (2x4), wave tile 32x32; grid 256 = 1 block/CU.
// LDS-traffic-minimized core: B (weights) staged via global_load_lds into a 5-slot
// 16KB ring (single barrier per K-step; WAR distance 4 mod 5 = safe). A-fragments
// load DIRECTLY global->VGPR with a 3-ahead 4-slot register pipeline (static slot
// indexing via unroll-by-4). 6 homogeneous VMEM issues/iter -> counted vmcnt ladder
// 18/12/6/0 never drains in-flight B prefetches.
// LDS bytes/K-step: 48KB (vs 88KB staged-A variant) -> predicted cadence ~850cy.
__global__ __launch_bounds__(512, 2) void k_lstm_step(
  const unsigned short* __restrict__ Ahi,
  const unsigned short* __restrict__ Whi,
  const float* __restrict__ addv, int addIsMat,
  float* __restrict__ cbuf,
  unsigned short* __restrict__ Hhi_out,
  const float* __restrict__ Wfc, float* __restrict__ pred, int tstep,
  int Kw, int NS)
{
  __shared__ char lds[81920];   // 5-slot B ring (16KB each); reused as gate buffer
  const int tid = threadIdx.x;
  const int wid = tid >> 6, lane = tid & 63;

  // XCD-grouped mapping: 32 blocks per XCD = 4 N-tiles x 8 M-tiles (grid 256, bijective)
  int L = blockIdx.x;
  int xc = L & 7, j = L >> 3;
  int ntile = xc * 4 + (j & 3);
  int mtile = j >> 2;
  int m0 = mtile * 64, n0 = ntile * 128;
  int wm = wid >> 2, wn = wid & 3;

  // ---- B staging: wave owns 2 x 1KB segments of each 16KB ring slot ----
  int rsub  = lane >> 3;                    // row within 8-row octet
  int col16 = (lane & 7) ^ rsub;            // pre-swizzled 16B-chunk column (involution)
  const unsigned short* gp0;
  const unsigned short* gp1;
  int segByte0, segByte1;
  {
    int sg0 = wid * 2, sg1 = wid * 2 + 1;
    gp0 = Whi + (size_t)(n0 + sg0 * 8 + rsub) * Kw + col16 * 8;
    gp1 = Whi + (size_t)(n0 + sg1 * 8 + rsub) * Kw + col16 * 8;
    segByte0 = sg0 * 1024;
    segByte1 = sg1 * 1024;
  }

  // ---- B fragment offsets (swizzled, slot-invariant) ----
  int offB[2][2];
  #pragma unroll
  for (int f = 0; f < 2; f++)
    #pragma unroll
    for (int ks = 0; ks < 2; ks++){
      int rowB = wn * 32 + f * 16 + (lane & 15);
      int kb   = ks * 64 + ((lane >> 4) << 4);
      offB[f][ks] = (rowB * 128 + kb) ^ ((rowB & 7) << 4);
    }

  // ---- A fragment global element-offsets (advance by 64 per K-step) ----
  int eA[2][2];
  #pragma unroll
  for (int f = 0; f < 2; f++)
    #pragma unroll
    for (int ks = 0; ks < 2; ks++)
      eA[f][ks] = (m0 + wm * 32 + f * 16 + (lane & 15)) * 2048
                + ks * 32 + ((lane >> 4) << 3);

  bf16x8 aReg[4][2][2];        // 4-slot A pipeline (all indices static below)
  f32x4 acc[2][2];
  #pragma unroll
  for (int a = 0; a < 2; a++)
    #pragma unroll
    for (int b = 0; b < 2; b++)
      acc[a][b] = (f32x4){0.f, 0.f, 0.f, 0.f};

  auto STAGE = [&](int slot){
    char* b = lds + slot * 16384;
    GLOAD16(gp0, b + segByte0); gp0 += 64;
    GLOAD16(gp1, b + segByte1); gp1 += 64;
  };

  #define LOADA(SL, ST) { int kk = (ST) * 64;                                  \
    aReg[SL][0][0] = *(const bf16x8*)(Ahi + eA[0][0] + kk);                    \
    aReg[SL][0][1] = *(const bf16x8*)(Ahi + eA[0][1] + kk);                    \
    aReg[SL][1][0] = *(const bf16x8*)(Ahi + eA[1][0] + kk);                    \
    aReg[SL][1][1] = *(const bf16x8*)(Ahi + eA[1][1] + kk); }

  // prologue: 3 steps in flight (A slots 0..2, ring slots 0..2)
  LOADA(0, 0); STAGE(0);
  LOADA(1, 1); STAGE(1);
  LOADA(2, 2); STAGE(2);

  int rc = 0;                   // ring slot being computed
  int rt = 3;                   // ring slot being staged (s+3)%5

  #define ITER(S, C) {                                                         \
    if ((S) + 3 < NS){ LOADA(((C) + 3) & 3, (S) + 3); STAGE(rt); }             \
    rt++; if (rt >= 5) rt = 0;                                                 \
    if ((S) + 3 < NS)      { asm volatile("s_waitcnt vmcnt(18)" ::: "memory"); } \
    else if ((S) + 2 < NS) { asm volatile("s_waitcnt vmcnt(12)" ::: "memory"); } \
    else if ((S) + 1 < NS) { asm volatile("s_waitcnt vmcnt(6)"  ::: "memory"); } \
    else                   { asm volatile("s_waitcnt vmcnt(0)"  ::: "memory"); } \
    __builtin_amdgcn_s_barrier();                                              \
    asm volatile("" ::: "memory");                                             \
    { const char* bb = lds + rc * 16384;                                       \
      _Pragma("unroll")                                                        \
      for (int ks = 0; ks < 2; ks++){                                          \
        bf16x8 b0 = *(const bf16x8*)(bb + offB[0][ks]);                        \
        bf16x8 b1 = *(const bf16x8*)(bb + offB[1][ks]);                        \
        acc[0][0] = mfma16(aReg[C][0][ks], b0, acc[0][0]);                     \
        acc[0][1] = mfma16(aReg[C][0][ks], b1, acc[0][1]);                     \
        acc[1][0] = mfma16(aReg[C][1][ks], b0, acc[1][0]);                     \
        acc[1][1] = mfma16(aReg[C][1][ks], b1, acc[1][1]);                     \
      }                                                                        \
    }                                                                          \
    rc++; if (rc >= 5) rc = 0;                                                 \
  }

  for (int s = 0; s < NS; s += 4){       // NS is a multiple of 4 (16 or 32)
    ITER(s + 0, 0);
    ITER(s + 1, 1);
    ITER(s + 2, 2);
    ITER(s + 3, 3);
  }
  #undef ITER
  #undef LOADA

  __syncthreads();   // all waves done reading B ring before LDS reuse

  // ---------- epilogue: acc -> LDS gates [64][129], then pointwise LSTM ----------
  float* gl = (float*)lds;
  #pragma unroll
  for (int fm = 0; fm < 2; fm++)
    #pragma unroll
    for (int fn = 0; fn < 2; fn++)
      #pragma unroll
      for (int r = 0; r < 4; r++){
        int row = wm * 32 + fm * 16 + ((lane >> 4) << 2) + r;   // batch row in tile
        int col = wn * 32 + fn * 16 + (lane & 15);              // gate col in tile
        gl[row * 129 + col] = acc[fm][fn][r];
      }
  __syncthreads();

  #pragma unroll
  for (int it = 0; it < 4; it++){
    int u    = tid & 31;                 // unit 0..31 within tile
    int rowl = (it << 4) + (tid >> 5);   // batch row 0..63 within tile
    int gm = m0 + rowl;
    int gu = (n0 >> 2) + u;              // global unit 0..1023
    const float* grow = gl + rowl * 129 + (u << 2);
    float gi = grow[0], gf = grow[1], gg = grow[2], go = grow[3];
    if (addIsMat){
      const float* a = addv + ((size_t)gm << 12) + n0 + (u << 2);
      gi += a[0]; gf += a[1]; gg += a[2]; go += a[3];
    } else {
      const float* a = addv + n0 + (u << 2);
      gi += a[0]; gf += a[1]; gg += a[2]; go += a[3];
    }
    float ii = 1.f / (1.f + expf(-gi));
    float ff = 1.f / (1.f + expf(-gf));
    float g2 = tanhf(gg);
    float oo = 1.f / (1.f + expf(-go));
    size_t ci = ((size_t)gm << 10) + gu;
    float c = ff * cbuf[ci] + ii * g2;
    cbuf[ci] = c;
    float h = oo * tanhf(c);
    size_t hi_idx = ((size_t)gm << 11) + gu;   // XA row stride 2048 (base pre-offset per layer)
    Hhi_out[hi_idx] = f2bf(h);
    if (pred){
      float p0 = h * Wfc[gu];
      float p1 = h * Wfc[1024 + gu];
      #pragma unroll
      for (int mm = 16; mm >= 1; mm >>= 1){
        p0 += __shfl_xor(p0, mm);
        p1 += __shfl_xor(p1, mm);
      }
      if ((lane & 31) == 0){
        float* op = pred + ((size_t)gm * 106 + tstep) * 2;
        atomicAdd(op,     p0);
        atomicAdd(op + 1, p1);
      }
    }
  }
}

// ---------------- launch ----------------
extern "C" void kernel_launch(void* const* d_in, const int* in_sizes, int n_in,
                              void* d_out, int out_size, void* d_ws, size_t ws_size,
                              hipStream_t stream)
{
  (void)in_sizes; (void)n_in; (void)out_size; (void)ws_size;
  const float* x    = (const float*)d_in[0];
  const float* Wih0 = (const float*)d_in[1];
  const float* Whh0 = (const float*)d_in[2];
  const float* bih0 = (const float*)d_in[3];
  const float* bhh0 = (const float*)d_in[4];
  const float* Wih1 = (const float*)d_in[5];
  const float* Whh1 = (const float*)d_in[6];
  const float* bih1 = (const float*)d_in[7];
  const float* bhh1 = (const float*)d_in[8];
  const float* Wfc  = (const float*)d_in[9];
  const float* bfc  = (const float*)d_in[10];
  float* out = (float*)d_out;

  char* ws = (char*)d_ws;
  size_t off = 0;
  auto carve = [&](size_t bytes)->char*{
    char* p = ws + off;
    off += (bytes + 255) & ~(size_t)255;
    return p;
  };
  unsigned short* W0hi = (unsigned short*)carve((size_t)4096 * 1024 * 2);
  unsigned short* W1hi = (unsigned short*)carve((size_t)4096 * 2048 * 2);
  float*          xb0  = (float*)carve((size_t)512 * 4096 * 4);
  float*          b1r  = (float*)carve((size_t)4096 * 4);
  unsigned short* XAhi = (unsigned short*)carve((size_t)2 * 512 * 2048 * 2);
  float*          c0   = (float*)carve((size_t)512 * 1024 * 4);
  float*          c1   = (float*)carve((size_t)512 * 1024 * 4);

  k_prep_w<<<dim3(2048), dim3(256), 0, stream>>>(Whh0, Wih1, Whh1, W0hi, W1hi);
  k_prep_misc<<<dim3(2048), dim3(256), 0, stream>>>(x, Wih0, bih0, bhh0, bih1, bhh1, bfc,
                                                    xb0, b1r, XAhi, c0, c1, out);

  const int PS = 512 * 2048;   // parity stride (elements) of XA
  for (int t = 0; t < 106; t++){
    int p = t & 1;
    // layer 0: gates = h0(t-1) @ W0^T + xb0 ; A = XA[p^1] cols 0..1023 ; K=1024, NS=16
    k_lstm_step<<<dim3(256), dim3(512), 0, stream>>>(
      XAhi + (p ^ 1) * PS,
      W0hi, xb0, 1, c0,
      XAhi + p * PS,                                // h0(t) -> XA[p] cols 0..1023
      (const float*)nullptr, (float*)nullptr, t, 1024, 16);
    // layer 1: gates = [h0(t)|h1(t-1)] @ W1^T + b1 ; A = XA[p] ; K=2048, NS=32 ; + FC
    k_lstm_step<<<dim3(256), dim3(512), 0, stream>>>(
      XAhi + p * PS,
      W1hi, b1r, 0, c1,
      XAhi + (p ^ 1) * PS + 1024,                   // h1(t) -> XA[p^1] cols 1024..
      Wfc, out, t, 2048, 32);
  }
}

// Round 11
// 3806.158 us; speedup vs baseline: 1.9416x; 1.7548x over previous
//
#include <hip/hip_runtime.h>
#include <stdint.h>

// ---------------- types / helpers ----------------
typedef short bf16x8 __attribute__((ext_vector_type(8)));
typedef float f32x4  __attribute__((ext_vector_type(4)));

__device__ static inline unsigned short f2bf(float v){
  unsigned x = __float_as_uint(v);
  unsigned r = (x + 0x7fffu + ((x >> 16) & 1u)) >> 16;
  return (unsigned short)r;
}

#define GLOAD16(g, l) \
  __builtin_amdgcn_global_load_lds((const __attribute__((address_space(1))) void*)(g), \
                                   (__attribute__((address_space(3))) void*)(l), 16, 0, 0)

__device__ static inline f32x4 mfma16(bf16x8 a, bf16x8 b, f32x4 c){
  return __builtin_amdgcn_mfma_f32_16x16x32_bf16(a, b, c, 0, 0, 0);
}

// ---------------- prep: weight bf16 round + gate-interleave reorder ----------------
__global__ void k_prep_w(const float* __restrict__ Whh0,
                         const float* __restrict__ Wih1, const float* __restrict__ Whh1,
                         unsigned short* __restrict__ W0hi, unsigned short* __restrict__ W1hi)
{
  const long n0 = (long)4096 * 1024;
  const long n1 = (long)4096 * 2048;
  long stride = (long)gridDim.x * blockDim.x;
  for (long idx = (long)blockIdx.x * blockDim.x + threadIdx.x; idx < n0 + n1; idx += stride){
    if (idx < n0){
      int i = (int)idx;
      int r = i >> 10, k = i & 1023;
      int u = r >> 2, g = r & 3;
      W0hi[i] = f2bf(Whh0[(size_t)(g * 1024 + u) * 1024 + k]);
    } else {
      long i = idx - n0;
      int r = (int)(i >> 11), k = (int)(i & 2047);
      int u = r >> 2, g = r & 3;
      int srow = g * 1024 + u;
      float v = (k < 1024) ? Wih1[(size_t)srow * 1024 + k]
                           : Whh1[(size_t)srow * 1024 + (k - 1024)];
      W1hi[i] = f2bf(v);
    }
  }
}

// ---------------- prep: x-proj+bias (reordered), b1r, zero states, init out ----------------
__global__ void k_prep_misc(const float* __restrict__ x, const float* __restrict__ Wih0,
                            const float* __restrict__ bih0, const float* __restrict__ bhh0,
                            const float* __restrict__ bih1, const float* __restrict__ bhh1,
                            const float* __restrict__ bfc,
                            float* __restrict__ xb0, float* __restrict__ b1r,
                            unsigned short* __restrict__ XAhi,
                            float* __restrict__ c0, float* __restrict__ c1,
                            float* __restrict__ out)
{
  const long NXB = (long)512 * 4096;
  const long NXA = (long)2 * 512 * 2048;
  const long NC  = (long)512 * 1024;
  const long NO  = (long)512 * 106 * 2;
  const long total = NXB + 4096 + NXA + 2 * NC + NO;
  long stride = (long)gridDim.x * blockDim.x;
  for (long idx = (long)blockIdx.x * blockDim.x + threadIdx.x; idx < total; idx += stride){
    long t = idx;
    if (t < NXB){
      int m = (int)(t >> 12), c = (int)(t & 4095);
      int u = c >> 2, g = c & 3;
      int row = g * 1024 + u;
      xb0[t] = x[m * 2 + 0] * Wih0[row * 2 + 0] + x[m * 2 + 1] * Wih0[row * 2 + 1]
             + bih0[row] + bhh0[row];
      continue;
    }
    t -= NXB;
    if (t < 4096){
      int c = (int)t; int u = c >> 2, g = c & 3; int row = g * 1024 + u;
      b1r[c] = bih1[row] + bhh1[row]; continue;
    }
    t -= 4096;
    if (t < NXA){ XAhi[t] = 0; continue; } t -= NXA;
    if (t < NC){ c0[t] = 0.f; continue; } t -= NC;
    if (t < NC){ c1[t] = 0.f; continue; } t -= NC;
    out[t] = bfc[t & 1];
  }
}

// ---------------- fused step kernel: bf16 GEMM + LSTM pointwise (+FC) ----------------
// gates[m, 4u+g] = sum_k A[m,k]*W[4u+g,k] ; single bf16 product.
// Tile BM=64, BN=64, BK=64; 4 waves (2x2), wave tile 32x32; grid 512 = 2 blocks/CU
// (64KB LDS). Rationale: 2 independent blocks/CU decouple barrier stalls (r2 vs r5
// evidence: same 8 waves/CU, but per-unit-work r2 was ~1.8x more efficient).
// 4-stage LDS ring (16KB/stage: A 8K|B 8K), 3-ahead prefetch, counted vmcnt 12/8/4/0.
// A rows live in XA [512][2048] bf16, row stride 2048 elements.
__global__ __launch_bounds__(256, 2) void k_lstm_step(
  const unsigned short* __restrict__ Ahi,
  const unsigned short* __restrict__ Whi,
  const float* __restrict__ addv, int addIsMat,
  float* __restrict__ cbuf,
  unsigned short* __restrict__ Hhi_out,
  const float* __restrict__ Wfc, float* __restrict__ pred, int tstep,
  int Kw, int NS)
{
  __shared__ char lds[65536];   // 4 stage buffers x 16KB
  const int tid = threadIdx.x;
  const int wid = tid >> 6, lane = tid & 63;

  // XCD-grouped mapping: 64 blocks per XCD = 8 N-tiles x 8 M-tiles (grid 512, bijective)
  int L = blockIdx.x;
  int xc = L & 7, j = L >> 3;
  int ntile = xc * 8 + (j & 7);          // 0..63
  int mtile = j >> 3;                    // 0..7
  int m0 = mtile * 64, n0 = ntile * 64;
  int wm = wid >> 1, wn = wid & 1;

  // ---- staging state (hoisted): wave owns 4 x 1KB segments of the 16KB stage ----
  // segs 0..7 = A rows (64 x 128B), segs 8..15 = B rows (64 x 128B)
  int rsub  = lane >> 3;                    // row within 8-row octet
  int col16 = (lane & 7) ^ rsub;            // pre-swizzled 16B-chunk column (involution)
  const unsigned short* gp[4];              // per-segment global pointers, advance 64/stage
  int segByte[4];                           // wave-uniform LDS byte offset within stage
  #pragma unroll
  for (int i = 0; i < 4; i++){
    int sg = wid * 4 + i;
    if (sg < 8){
      int row = sg * 8 + rsub;              // A row 0..63
      gp[i] = Ahi + (size_t)(m0 + row) * 2048 + col16 * 8;
    } else {
      int row = (sg - 8) * 8 + rsub;        // B row 0..63
      gp[i] = Whi + (size_t)(n0 + row) * Kw + col16 * 8;
    }
    segByte[i] = sg * 1024;
  }

  // ---- compute-side swizzled fragment offsets (stage-invariant) ----
  int offA[2][2], offB[2][2];
  #pragma unroll
  for (int f = 0; f < 2; f++)
    #pragma unroll
    for (int ks = 0; ks < 2; ks++){
      int rowA = wm * 32 + f * 16 + (lane & 15);
      int rowB = wn * 32 + f * 16 + (lane & 15);
      int kb   = ks * 64 + ((lane >> 4) << 4);
      offA[f][ks] = (rowA * 128 + kb) ^ ((rowA & 7) << 4);
      offB[f][ks] = 8192 + ((rowB * 128 + kb) ^ ((rowB & 7) << 4));
    }

  f32x4 acc[2][2];
  #pragma unroll
  for (int a = 0; a < 2; a++)
    #pragma unroll
    for (int b = 0; b < 2; b++)
      acc[a][b] = (f32x4){0.f, 0.f, 0.f, 0.f};

  auto STAGE = [&](int sbuf){
    char* ldsb = lds + sbuf * 16384;
    #pragma unroll
    for (int i = 0; i < 4; i++){
      GLOAD16(gp[i], ldsb + segByte[i]);
      gp[i] += 64;
    }
  };

  STAGE(0); STAGE(1); STAGE(2);
  int cur = 0;
  for (int s = 0; s < NS; s++){
    if (s + 3 < NS){
      STAGE((cur + 3) & 3);
      asm volatile("s_waitcnt vmcnt(12)" ::: "memory");  // stage s landed; s+1..s+3 in flight
    } else if (s + 2 < NS){
      asm volatile("s_waitcnt vmcnt(8)" ::: "memory");
    } else if (s + 1 < NS){
      asm volatile("s_waitcnt vmcnt(4)" ::: "memory");
    } else {
      asm volatile("s_waitcnt vmcnt(0)" ::: "memory");
    }
    __builtin_amdgcn_s_barrier();
    asm volatile("" ::: "memory");

    const char* bb = lds + cur * 16384;
    #pragma unroll
    for (int ks = 0; ks < 2; ks++){
      bf16x8 ah0 = *(const bf16x8*)(bb + offA[0][ks]);
      bf16x8 ah1 = *(const bf16x8*)(bb + offA[1][ks]);
      bf16x8 bh0 = *(const bf16x8*)(bb + offB[0][ks]);
      bf16x8 bh1 = *(const bf16x8*)(bb + offB[1][ks]);
      acc[0][0] = mfma16(ah0, bh0, acc[0][0]);
      acc[0][1] = mfma16(ah0, bh1, acc[0][1]);
      acc[1][0] = mfma16(ah1, bh0, acc[1][0]);
      acc[1][1] = mfma16(ah1, bh1, acc[1][1]);
    }
    asm volatile("" ::: "memory");
    __builtin_amdgcn_s_barrier();
    cur = (cur + 1) & 3;
  }

  // ---------- epilogue: acc -> LDS gates [64][65], then pointwise LSTM ----------
  float* gl = (float*)lds;
  #pragma unroll
  for (int fm = 0; fm < 2; fm++)
    #pragma unroll
    for (int fn = 0; fn < 2; fn++)
      #pragma unroll
      for (int r = 0; r < 4; r++){
        int row = wm * 32 + fm * 16 + ((lane >> 4) << 2) + r;   // batch row in tile
        int col = wn * 32 + fn * 16 + (lane & 15);              // gate col in tile
        gl[row * 65 + col] = acc[fm][fn][r];
      }
  __syncthreads();

  #pragma unroll
  for (int it = 0; it < 4; it++){
    int u    = tid & 15;                 // unit 0..15 within tile
    int rowl = (it << 4) + (tid >> 4);   // batch row 0..63 within tile
    int gm = m0 + rowl;
    int gu = (n0 >> 2) + u;              // global unit 0..1023
    const float* grow = gl + rowl * 65 + (u << 2);
    float gi = grow[0], gf = grow[1], gg = grow[2], go = grow[3];
    if (addIsMat){
      const float* a = addv + ((size_t)gm << 12) + n0 + (u << 2);
      gi += a[0]; gf += a[1]; gg += a[2]; go += a[3];
    } else {
      const float* a = addv + n0 + (u << 2);
      gi += a[0]; gf += a[1]; gg += a[2]; go += a[3];
    }
    float ii = 1.f / (1.f + expf(-gi));
    float ff = 1.f / (1.f + expf(-gf));
    float g2 = tanhf(gg);
    float oo = 1.f / (1.f + expf(-go));
    size_t ci = ((size_t)gm << 10) + gu;
    float c = ff * cbuf[ci] + ii * g2;
    cbuf[ci] = c;
    float h = oo * tanhf(c);
    size_t hi_idx = ((size_t)gm << 11) + gu;   // XA row stride 2048 (base pre-offset per layer)
    Hhi_out[hi_idx] = f2bf(h);
    if (pred){
      float p0 = h * Wfc[gu];
      float p1 = h * Wfc[1024 + gu];
      #pragma unroll
      for (int mm = 8; mm >= 1; mm >>= 1){
        p0 += __shfl_xor(p0, mm);
        p1 += __shfl_xor(p1, mm);
      }
      if ((lane & 15) == 0){
        float* op = pred + ((size_t)gm * 106 + tstep) * 2;
        atomicAdd(op,     p0);
        atomicAdd(op + 1, p1);
      }
    }
  }
}

// ---------------- launch ----------------
extern "C" void kernel_launch(void* const* d_in, const int* in_sizes, int n_in,
                              void* d_out, int out_size, void* d_ws, size_t ws_size,
                              hipStream_t stream)
{
  (void)in_sizes; (void)n_in; (void)out_size; (void)ws_size;
  const float* x    = (const float*)d_in[0];
  const float* Wih0 = (const float*)d_in[1];
  const float* Whh0 = (const float*)d_in[2];
  const float* bih0 = (const float*)d_in[3];
  const float* bhh0 = (const float*)d_in[4];
  const float* Wih1 = (const float*)d_in[5];
  const float* Whh1 = (const float*)d_in[6];
  const float* bih1 = (const float*)d_in[7];
  const float* bhh1 = (const float*)d_in[8];
  const float* Wfc  = (const float*)d_in[9];
  const float* bfc  = (const float*)d_in[10];
  float* out = (float*)d_out;

  char* ws = (char*)d_ws;
  size_t off = 0;
  auto carve = [&](size_t bytes)->char*{
    char* p = ws + off;
    off += (bytes + 255) & ~(size_t)255;
    return p;
  };
  unsigned short* W0hi = (unsigned short*)carve((size_t)4096 * 1024 * 2);
  unsigned short* W1hi = (unsigned short*)carve((size_t)4096 * 2048 * 2);
  float*          xb0  = (float*)carve((size_t)512 * 4096 * 4);
  float*          b1r  = (float*)carve((size_t)4096 * 4);
  unsigned short* XAhi = (unsigned short*)carve((size_t)2 * 512 * 2048 * 2);
  float*          c0   = (float*)carve((size_t)512 * 1024 * 4);
  float*          c1   = (float*)carve((size_t)512 * 1024 * 4);

  k_prep_w<<<dim3(2048), dim3(256), 0, stream>>>(Whh0, Wih1, Whh1, W0hi, W1hi);
  k_prep_misc<<<dim3(2048), dim3(256), 0, stream>>>(x, Wih0, bih0, bhh0, bih1, bhh1, bfc,
                                                    xb0, b1r, XAhi, c0, c1, out);

  const int PS = 512 * 2048;   // parity stride (elements) of XA
  for (int t = 0; t < 106; t++){
    int p = t & 1;
    // layer 0: gates = h0(t-1) @ W0^T + xb0 ; A = XA[p^1] cols 0..1023 ; K=1024, NS=16
    k_lstm_step<<<dim3(512), dim3(256), 0, stream>>>(
      XAhi + (p ^ 1) * PS,
      W0hi, xb0, 1, c0,
      XAhi + p * PS,                                // h0(t) -> XA[p] cols 0..1023
      (const float*)nullptr, (float*)nullptr, t, 1024, 16);
    // layer 1: gates = [h0(t)|h1(t-1)] @ W1^T + b1 ; A = XA[p] ; K=2048, NS=32 ; + FC
    k_lstm_step<<<dim3(512), dim3(256), 0, stream>>>(
      XAhi + p * PS,
      W1hi, b1r, 0, c1,
      XAhi + (p ^ 1) * PS + 1024,                   // h1(t) -> XA[p^1] cols 1024..
      Wfc, out, t, 2048, 32);
  }
}

// Round 12
// 2593.162 us; speedup vs baseline: 2.8498x; 1.4678x over previous
//
#include <hip/hip_runtime.h>
#include <stdint.h>

// ---------------- types / helpers ----------------
typedef short bf16x8 __attribute__((ext_vector_type(8)));
typedef float f32x4  __attribute__((ext_vector_type(4)));

__device__ static inline unsigned short f2bf(float v){
  unsigned x = __float_as_uint(v);
  unsigned r = (x + 0x7fffu + ((x >> 16) & 1u)) >> 16;
  return (unsigned short)r;
}

#define GLOAD16(g, l) \
  __builtin_amdgcn_global_load_lds((const __attribute__((address_space(1))) void*)(g), \
                                   (__attribute__((address_space(3))) void*)(l), 16, 0, 0)

__device__ static inline f32x4 mfma16(bf16x8 a, bf16x8 b, f32x4 c){
  return __builtin_amdgcn_mfma_f32_16x16x32_bf16(a, b, c, 0, 0, 0);
}

// ---------------- prep: weight bf16 round + gate-interleave reorder ----------------
__global__ void k_prep_w(const float* __restrict__ Whh0,
                         const float* __restrict__ Wih1, const float* __restrict__ Whh1,
                         unsigned short* __restrict__ W0hi, unsigned short* __restrict__ W1hi)
{
  const long n0 = (long)4096 * 1024;
  const long n1 = (long)4096 * 2048;
  long stride = (long)gridDim.x * blockDim.x;
  for (long idx = (long)blockIdx.x * blockDim.x + threadIdx.x; idx < n0 + n1; idx += stride){
    if (idx < n0){
      int i = (int)idx;
      int r = i >> 10, k = i & 1023;
      int u = r >> 2, g = r & 3;
      W0hi[i] = f2bf(Whh0[(size_t)(g * 1024 + u) * 1024 + k]);
    } else {
      long i = idx - n0;
      int r = (int)(i >> 11), k = (int)(i & 2047);
      int u = r >> 2, g = r & 3;
      int srow = g * 1024 + u;
      float v = (k < 1024) ? Wih1[(size_t)srow * 1024 + k]
                           : Whh1[(size_t)srow * 1024 + (k - 1024)];
      W1hi[i] = f2bf(v);
    }
  }
}

// ---------------- prep: x-proj+bias (reordered), b1r, zero states, init out ----------------
__global__ void k_prep_misc(const float* __restrict__ x, const float* __restrict__ Wih0,
                            const float* __restrict__ bih0, const float* __restrict__ bhh0,
                            const float* __restrict__ bih1, const float* __restrict__ bhh1,
                            const float* __restrict__ bfc,
                            float* __restrict__ xb0, float* __restrict__ b1r,
                            unsigned short* __restrict__ XAhi,
                            float* __restrict__ c0, float* __restrict__ c1,
                            float* __restrict__ out)
{
  const long NXB = (long)512 * 4096;
  const long NXA = (long)2 * 512 * 2048;
  const long NC  = (long)512 * 1024;
  const long NO  = (long)512 * 106 * 2;
  const long total = NXB + 4096 + NXA + 2 * NC + NO;
  long stride = (long)gridDim.x * blockDim.x;
  for (long idx = (long)blockIdx.x * blockDim.x + threadIdx.x; idx < total; idx += stride){
    long t = idx;
    if (t < NXB){
      int m = (int)(t >> 12), c = (int)(t & 4095);
      int u = c >> 2, g = c & 3;
      int row = g * 1024 + u;
      xb0[t] = x[m * 2 + 0] * Wih0[row * 2 + 0] + x[m * 2 + 1] * Wih0[row * 2 + 1]
             + bih0[row] + bhh0[row];
      continue;
    }
    t -= NXB;
    if (t < 4096){
      int c = (int)t; int u = c >> 2, g = c & 3; int row = g * 1024 + u;
      b1r[c] = bih1[row] + bhh1[row]; continue;
    }
    t -= 4096;
    if (t < NXA){ XAhi[t] = 0; continue; } t -= NXA;
    if (t < NC){ c0[t] = 0.f; continue; } t -= NC;
    if (t < NC){ c1[t] = 0.f; continue; } t -= NC;
    out[t] = bfc[t & 1];
  }
}

// ---------------- merged step kernel: L1(t) and L0(t+1) in one dispatch ----------------
// Both parts read XAr (h0(t) cols 0:1024, h1(t-1) cols 1024:2048) and write disjoint
// halves of XAw. mode: 0 = merged (512 blocks: [0,256)=L1, [256,512)=L0),
// 1 = L0-only (256 blocks, pipeline head), 2 = L1-only (256 blocks, tail).
// Per block: tile BM=64, BN=128, BK=64; 8 waves (2x4), wave tile 32x32.
// 3-stage LDS ring (24KB/stage: A 8K|B 16K) = 72KB -> 2 blocks/CU in merged mode
// (cross-layer co-residency overlaps barrier/vmcnt stalls). 2-ahead counted vmcnt 6/3/0.
__global__ __launch_bounds__(512, 4) void k_lstm_step(
  const unsigned short* __restrict__ XAr,
  unsigned short* __restrict__ XAw,
  const unsigned short* __restrict__ W0, const unsigned short* __restrict__ W1,
  const float* __restrict__ xb0, const float* __restrict__ b1r,
  float* __restrict__ c0, float* __restrict__ c1,
  const float* __restrict__ Wfc, float* __restrict__ out,
  int tstep, int mode)
{
  __shared__ char lds[73728];   // 3 stage buffers x 24KB
  const int tid = threadIdx.x;
  const int wid = tid >> 6, lane = tid & 63;

  int L = blockIdx.x;
  bool isL1;
  if (mode == 0){ isL1 = (L < 256); L &= 255; }
  else          { isL1 = (mode == 2); }

  const unsigned short* Whi  = isL1 ? W1 : W0;
  const float*          addv = isL1 ? b1r : xb0;
  const int         addIsMat = isL1 ? 0 : 1;
  float*                cbuf = isL1 ? c1 : c0;
  unsigned short*       Hout = XAw + (isL1 ? 1024 : 0);
  float*                pred = isL1 ? out : nullptr;
  const int               Kw = isL1 ? 2048 : 1024;
  const int               NS = isL1 ? 32 : 16;

  // XCD-grouped mapping: 32 blocks per XCD = 4 N-tiles x 8 M-tiles (per half, bijective)
  int xc = L & 7, j = L >> 3;
  int ntile = xc * 4 + (j & 3);
  int mtile = j >> 2;
  int m0 = mtile * 64, n0 = ntile * 128;
  int wm = wid >> 2, wn = wid & 3;

  // ---- staging state (hoisted): wave owns 3 x 1KB segments of the 24KB stage ----
  // segment sg: [0,8)=A row-octet sg, [8,24)=B (weight rows n0..n0+127)
  int rsub  = lane >> 3;                    // row within 8-row octet
  int col16 = (lane & 7) ^ rsub;            // pre-swizzled 16B-chunk column (involution)
  const unsigned short* gp[3];              // per-segment global pointers, advance 64/step
  int segByte[3];                           // wave-uniform LDS byte offset within stage
  #pragma unroll
  for (int i = 0; i < 3; i++){
    int sg = wid * 3 + i;
    int tb, local;
    const unsigned short* base;
    bool isA;
    if (sg < 8) { tb = 0;    local = sg;     base = XAr; isA = true;  }
    else        { tb = 8192; local = sg - 8; base = Whi; isA = false; }
    int row = local * 8 + rsub;
    gp[i] = isA ? (base + (size_t)(m0 + row) * 2048 + col16 * 8)
                : (base + (size_t)(n0 + row) * Kw   + col16 * 8);
    segByte[i] = tb + local * 1024;
  }

  // ---- compute-side swizzled fragment offsets (stage-invariant) ----
  int offA[2][2], offB[2][2];
  #pragma unroll
  for (int f = 0; f < 2; f++)
    #pragma unroll
    for (int ks = 0; ks < 2; ks++){
      int rowA = wm * 32 + f * 16 + (lane & 15);
      int rowB = wn * 32 + f * 16 + (lane & 15);
      int kb   = ks * 64 + ((lane >> 4) << 4);
      offA[f][ks] = (rowA * 128 + kb) ^ ((rowA & 7) << 4);
      offB[f][ks] = 8192 + ((rowB * 128 + kb) ^ ((rowB & 7) << 4));
    }

  f32x4 acc[2][2];
  #pragma unroll
  for (int a = 0; a < 2; a++)
    #pragma unroll
    for (int b = 0; b < 2; b++)
      acc[a][b] = (f32x4){0.f, 0.f, 0.f, 0.f};

  auto STAGE = [&](int sbuf){
    char* ldsb = lds + sbuf * 24576;
    #pragma unroll
    for (int i = 0; i < 3; i++){
      GLOAD16(gp[i], ldsb + segByte[i]);
      gp[i] += 64;
    }
  };

  STAGE(0); STAGE(1);
  int cur = 0;
  for (int s = 0; s < NS; s++){
    if (s + 2 < NS){
      int nxt = cur + 2; if (nxt >= 3) nxt -= 3;
      STAGE(nxt);
      asm volatile("s_waitcnt vmcnt(6)" ::: "memory");   // stage s landed; s+1,s+2 in flight
    } else if (s + 1 < NS){
      asm volatile("s_waitcnt vmcnt(3)" ::: "memory");
    } else {
      asm volatile("s_waitcnt vmcnt(0)" ::: "memory");
    }
    __builtin_amdgcn_s_barrier();
    asm volatile("" ::: "memory");

    const char* bb = lds + cur * 24576;
    #pragma unroll
    for (int ks = 0; ks < 2; ks++){
      bf16x8 ah0 = *(const bf16x8*)(bb + offA[0][ks]);
      bf16x8 ah1 = *(const bf16x8*)(bb + offA[1][ks]);
      bf16x8 bh0 = *(const bf16x8*)(bb + offB[0][ks]);
      bf16x8 bh1 = *(const bf16x8*)(bb + offB[1][ks]);
      acc[0][0] = mfma16(ah0, bh0, acc[0][0]);
      acc[0][1] = mfma16(ah0, bh1, acc[0][1]);
      acc[1][0] = mfma16(ah1, bh0, acc[1][0]);
      acc[1][1] = mfma16(ah1, bh1, acc[1][1]);
    }
    asm volatile("" ::: "memory");
    __builtin_amdgcn_s_barrier();
    cur += 1; if (cur >= 3) cur -= 3;
  }

  // ---------- epilogue: acc -> LDS gates [64][129], then pointwise LSTM ----------
  float* gl = (float*)lds;
  #pragma unroll
  for (int fm = 0; fm < 2; fm++)
    #pragma unroll
    for (int fn = 0; fn < 2; fn++)
      #pragma unroll
      for (int r = 0; r < 4; r++){
        int row = wm * 32 + fm * 16 + ((lane >> 4) << 2) + r;   // batch row in tile
        int col = wn * 32 + fn * 16 + (lane & 15);              // gate col in tile
        gl[row * 129 + col] = acc[fm][fn][r];
      }
  __syncthreads();

  #pragma unroll
  for (int it = 0; it < 4; it++){
    int u    = tid & 31;                 // unit 0..31 within tile
    int rowl = (it << 4) + (tid >> 5);   // batch row 0..63 within tile
    int gm = m0 + rowl;
    int gu = (n0 >> 2) + u;              // global unit 0..1023
    const float* grow = gl + rowl * 129 + (u << 2);
    float gi = grow[0], gf = grow[1], gg = grow[2], go = grow[3];
    if (addIsMat){
      const float* a = addv + ((size_t)gm << 12) + n0 + (u << 2);
      gi += a[0]; gf += a[1]; gg += a[2]; go += a[3];
    } else {
      const float* a = addv + n0 + (u << 2);
      gi += a[0]; gf += a[1]; gg += a[2]; go += a[3];
    }
    float ii = 1.f / (1.f + expf(-gi));
    float ff = 1.f / (1.f + expf(-gf));
    float g2 = tanhf(gg);
    float oo = 1.f / (1.f + expf(-go));
    size_t ci = ((size_t)gm << 10) + gu;
    float c = ff * cbuf[ci] + ii * g2;
    cbuf[ci] = c;
    float h = oo * tanhf(c);
    size_t hi_idx = ((size_t)gm << 11) + gu;   // XA row stride 2048
    Hout[hi_idx] = f2bf(h);
    if (pred){
      float p0 = h * Wfc[gu];
      float p1 = h * Wfc[1024 + gu];
      #pragma unroll
      for (int mm = 16; mm >= 1; mm >>= 1){
        p0 += __shfl_xor(p0, mm);
        p1 += __shfl_xor(p1, mm);
      }
      if ((lane & 31) == 0){
        float* op = pred + ((size_t)gm * 106 + tstep) * 2;
        atomicAdd(op,     p0);
        atomicAdd(op + 1, p1);
      }
    }
  }
}

// ---------------- launch ----------------
extern "C" void kernel_launch(void* const* d_in, const int* in_sizes, int n_in,
                              void* d_out, int out_size, void* d_ws, size_t ws_size,
                              hipStream_t stream)
{
  (void)in_sizes; (void)n_in; (void)out_size; (void)ws_size;
  const float* x    = (const float*)d_in[0];
  const float* Wih0 = (const float*)d_in[1];
  const float* Whh0 = (const float*)d_in[2];
  const float* bih0 = (const float*)d_in[3];
  const float* bhh0 = (const float*)d_in[4];
  const float* Wih1 = (const float*)d_in[5];
  const float* Whh1 = (const float*)d_in[6];
  const float* bih1 = (const float*)d_in[7];
  const float* bhh1 = (const float*)d_in[8];
  const float* Wfc  = (const float*)d_in[9];
  const float* bfc  = (const float*)d_in[10];
  float* out = (float*)d_out;

  char* ws = (char*)d_ws;
  size_t off = 0;
  auto carve = [&](size_t bytes)->char*{
    char* p = ws + off;
    off += (bytes + 255) & ~(size_t)255;
    return p;
  };
  unsigned short* W0hi = (unsigned short*)carve((size_t)4096 * 1024 * 2);
  unsigned short* W1hi = (unsigned short*)carve((size_t)4096 * 2048 * 2);
  float*          xb0  = (float*)carve((size_t)512 * 4096 * 4);
  float*          b1r  = (float*)carve((size_t)4096 * 4);
  unsigned short* XAhi = (unsigned short*)carve((size_t)2 * 512 * 2048 * 2);
  float*          c0   = (float*)carve((size_t)512 * 1024 * 4);
  float*          c1   = (float*)carve((size_t)512 * 1024 * 4);

  k_prep_w<<<dim3(2048), dim3(256), 0, stream>>>(Whh0, Wih1, Whh1, W0hi, W1hi);
  k_prep_misc<<<dim3(2048), dim3(256), 0, stream>>>(x, Wih0, bih0, bhh0, bih1, bhh1, bfc,
                                                    xb0, b1r, XAhi, c0, c1, out);

  const int PS = 512 * 2048;   // parity stride (elements) of XA

  // pipeline head: L0(0) reads XA[1] (zeros), writes h0(0) -> XA[0] cols 0:1024
  k_lstm_step<<<dim3(256), dim3(512), 0, stream>>>(
    XAhi + PS, XAhi, W0hi, W1hi, xb0, b1r, c0, c1, Wfc, out, 0, 1);

  // merged steps: D(tau) = L1(tau) + L0(tau+1); both read XA[tau&1], write XA[(tau&1)^1]
  for (int tau = 0; tau < 105; tau++){
    int p = tau & 1;
    k_lstm_step<<<dim3(512), dim3(512), 0, stream>>>(
      XAhi + p * PS, XAhi + (p ^ 1) * PS,
      W0hi, W1hi, xb0, b1r, c0, c1, Wfc, out, tau, 0);
  }

  // pipeline tail: L1(105) reads XA[1] (h0(105), h1(104)), FC pred t=105
  k_lstm_step<<<dim3(256), dim3(512), 0, stream>>>(
    XAhi + PS, XAhi, W0hi, W1hi, xb0, b1r, c0, c1, Wfc, out, 105, 2);
}